// Round 16
// baseline (300.395 us; speedup 1.0000x reference)
//
#include <hip/hip_runtime.h>
#include <hip/hip_bf16.h>
#include <math.h>

// Problem constants (from reference)
#define BATCH   32
#define NBLK    128
#define BLOCK_T 16
#define HEADS   16
#define DHEAD   128
#define HID     2048
#define FFN     8192
#define KV_LEN  2048

#define NSPLIT2 64            // splits per sequence (32 tokens each)
#define TOKSPL  32            // tokens per split

typedef float floatx4 __attribute__((ext_vector_type(4)));   // builtin-compatible
typedef float floatx2 __attribute__((ext_vector_type(2)));

// ---------------------------------------------------------------------------
// prep: RoPE cos/sin tables ([tok][64] freq-major) + embeddings
// ---------------------------------------------------------------------------
__global__ void prep_kernel(const int* __restrict__ ids, const int* __restrict__ pos,
                            const float* __restrict__ et, const float* __restrict__ ep,
                            float* __restrict__ c4f, float* __restrict__ s4f,
                            float* __restrict__ emb) {
    if (blockIdx.x < 512) {
        int s = blockIdx.x * 4 + (threadIdx.x >> 6);   // 0..2047
        int i = threadIdx.x & 63;
        float inv = powf(10000.0f, -(float)i / 64.0f);
        float ang = (float)s * inv;
        c4f[s * 64 + i] = cosf(ang);
        s4f[s * 64 + i] = sinf(ang);
    } else {
        int b = blockIdx.x - 512;
        int id = ids[b], p = pos[b];
        const float4* a = (const float4*)(et + (size_t)id * HID);
        const float4* d = (const float4*)(ep + (size_t)p * HID);
        float4* o = (float4*)(emb + (size_t)b * HID);
        for (int c = threadIdx.x; c < HID / 4; c += 256) {
            float4 x = a[c], y = d[c];
            o[c] = make_float4(x.x + y.x, x.y + y.y, x.z + y.z, x.w + y.w);
        }
    }
}

// ---------------------------------------------------------------------------
// Split-K skinny GEMM body: X[32][K] @ W[K][N] -> P[chunk][32][N] partials.
// Thread: 2 consecutive cols, all 32 batch rows. W rows are a single-use
// stream -> NON-TEMPORAL loads; P partials are write-once-read-once ->
// NON-TEMPORAL stores. 16-deep double-buffered prefetch. 512 cols per block.
// ---------------------------------------------------------------------------
template <int KC>
__device__ __forceinline__ void gemm2_body(
    const float* __restrict__ X, const float* __restrict__ W,
    float* __restrict__ P, int K, int N, int bx, int by, int tid) {
    __shared__ float xs[KC][36];
    const int k0 = by * KC;
    const int j  = bx * 512 + tid * 2;

    #pragma unroll
    for (int t = tid; t < 32 * KC / 4; t += 256) {
        int bb = t / (KC / 4), qq = t % (KC / 4);
        float4 xv = *reinterpret_cast<const float4*>(X + (size_t)bb * K + k0 + 4 * qq);
        xs[4 * qq + 0][bb] = xv.x; xs[4 * qq + 1][bb] = xv.y;
        xs[4 * qq + 2][bb] = xv.z; xs[4 * qq + 3][bb] = xv.w;
    }
    __syncthreads();

    float acc[32][2];
    #pragma unroll
    for (int bb = 0; bb < 32; ++bb) { acc[bb][0] = 0.f; acc[bb][1] = 0.f; }

    const float* wp = W + (size_t)k0 * N + j;
    floatx2 bufA[16], bufB[16];
    #pragma unroll
    for (int u = 0; u < 16; ++u)
        bufA[u] = __builtin_nontemporal_load(reinterpret_cast<const floatx2*>(wp + (size_t)u * N));

    #define G2_FMA16(BUF, KK)                                                   \
        _Pragma("unroll")                                                       \
        for (int u = 0; u < 16; ++u) {                                          \
            const floatx2 w = BUF[u];                                           \
            _Pragma("unroll")                                                   \
            for (int g = 0; g < 8; ++g) {                                       \
                const float4 xv = *reinterpret_cast<const float4*>(&xs[(KK) + u][g * 4]); \
                acc[4*g+0][0] = fmaf(xv.x, w[0], acc[4*g+0][0]);                \
                acc[4*g+0][1] = fmaf(xv.x, w[1], acc[4*g+0][1]);                \
                acc[4*g+1][0] = fmaf(xv.y, w[0], acc[4*g+1][0]);                \
                acc[4*g+1][1] = fmaf(xv.y, w[1], acc[4*g+1][1]);                \
                acc[4*g+2][0] = fmaf(xv.z, w[0], acc[4*g+2][0]);                \
                acc[4*g+2][1] = fmaf(xv.z, w[1], acc[4*g+2][1]);                \
                acc[4*g+3][0] = fmaf(xv.w, w[0], acc[4*g+3][0]);                \
                acc[4*g+3][1] = fmaf(xv.w, w[1], acc[4*g+3][1]);                \
            }                                                                   \
        }

    for (int kk = 0; kk < KC; kk += 32) {
        #pragma unroll
        for (int u = 0; u < 16; ++u)
            bufB[u] = __builtin_nontemporal_load(
                reinterpret_cast<const floatx2*>(wp + (size_t)(kk + 16 + u) * N));
        G2_FMA16(bufA, kk)
        #pragma unroll
        for (int u = 0; u < 16; ++u) {
            int rr = kk + 32 + u; rr = (rr < KC) ? rr : (KC - 1);
            bufA[u] = __builtin_nontemporal_load(
                reinterpret_cast<const floatx2*>(wp + (size_t)rr * N));
        }
        G2_FMA16(bufB, kk + 16)
    }
    #undef G2_FMA16

    float* pp = P + ((size_t)by * 32) * N + j;
    #pragma unroll
    for (int bb = 0; bb < 32; ++bb) {
        floatx2 v; v[0] = acc[bb][0]; v[1] = acc[bb][1];
        __builtin_nontemporal_store(v, reinterpret_cast<floatx2*>(pp + (size_t)bb * N));
    }
}

template <int KC>
__global__ __launch_bounds__(256) void gemm2_kernel(
    const float* __restrict__ X, const float* __restrict__ W,
    float* __restrict__ P, int K, int N) {
    gemm2_body<KC>(X, W, P, K, N, blockIdx.x, blockIdx.y, threadIdx.x);
}

// merged: blocks 0..255 -> ao@Wprm (Nsplit=4, SK=64); 256..511 -> ao@W1 (Nsplit=16, SK=16)
__global__ __launch_bounds__(256) void gemm2_dual_kernel(
    const float* __restrict__ X, const float* __restrict__ Wprm,
    const float* __restrict__ W1,
    float* __restrict__ Pprm, float* __restrict__ P1) {
    if (blockIdx.x < 256) {
        gemm2_body<32>(X, Wprm, Pprm, HID, HID, blockIdx.x & 3, blockIdx.x >> 2, threadIdx.x);
    } else {
        int bb = blockIdx.x - 256;
        gemm2_body<128>(X, W1, P1, HID, FFN, bb & 15, bb >> 4, threadIdx.x);
    }
}

// ---------------------------------------------------------------------------
// stage1 partial reduction: group g sums 8 chunks -> S[g][total4]
// P partials are read-once -> NON-TEMPORAL loads.
// ---------------------------------------------------------------------------
__global__ void red_stage1(const float* __restrict__ PA, const float* __restrict__ PB,
                           int ngA, float* __restrict__ S, int total4) {
    int idx4 = blockIdx.x * 256 + threadIdx.x;
    if (idx4 >= total4) return;
    int g = blockIdx.y;
    const floatx4* src = (const floatx4*)((g < ngA) ? PA : PB);
    int c0 = ((g < ngA) ? g : (g - ngA)) * 8;
    floatx4 s = {0.f, 0.f, 0.f, 0.f};
    #pragma unroll
    for (int c = 0; c < 8; ++c) {
        floatx4 v = __builtin_nontemporal_load(src + (size_t)(c0 + c) * total4 + idx4);
        s += v;
    }
    ((floatx4*)S)[(size_t)g * total4 + idx4] = s;
}

__global__ void red_stage2(const float* __restrict__ S, int ng, int total4,
                           float* __restrict__ out) {
    int idx4 = blockIdx.x * 256 + threadIdx.x;
    if (idx4 >= total4) return;
    floatx4 s = {0.f, 0.f, 0.f, 0.f};
    for (int g = 0; g < ng; ++g)
        s += ((const floatx4*)S)[(size_t)g * total4 + idx4];
    ((floatx4*)out)[idx4] = s;
}

// single-stage reduce (few chunks): out[idx4] = sum_c P[c][idx4], nt loads
__global__ void reduce4_kernel(const float* __restrict__ P, int nch, int total4,
                               float* __restrict__ out) {
    int idx4 = blockIdx.x * 256 + threadIdx.x;
    if (idx4 >= total4) return;
    const floatx4* P4 = (const floatx4*)P;
    floatx4 s = {0.f, 0.f, 0.f, 0.f};
    for (int c = 0; c < nch; ++c)
        s += __builtin_nontemporal_load(P4 + (size_t)c * total4 + idx4);
    ((floatx4*)out)[idx4] = s;
}

// ---------------------------------------------------------------------------
// Final Wq reduce (from S groups) + RoPE -> q[32][2048]
// ---------------------------------------------------------------------------
__global__ void rope_q_from_S(const float* __restrict__ S, int ng,
                              const int* __restrict__ positions,
                              const float* __restrict__ c4f, const float* __restrict__ s4f,
                              float* __restrict__ qout) {
    int idx = blockIdx.x * 256 + threadIdx.x;   // 32768 threads
    int i = idx & 63, hh = (idx >> 6) & 15, b = idx >> 10;
    int base = b * HID + hh * DHEAD;
    float q1 = 0.f, q2 = 0.f;
    for (int g = 0; g < ng; ++g) {
        q1 += S[(size_t)g * (BATCH * HID) + base + i];
        q2 += S[(size_t)g * (BATCH * HID) + base + 64 + i];
    }
    int pos = positions[b];
    float co = c4f[pos * 64 + i], si = s4f[pos * 64 + i];
    qout[base + i]      = q1 * co - q2 * si;
    qout[base + 64 + i] = q1 * si + q2 * co;
}

// ---------------------------------------------------------------------------
// Head-cooperative flash-decode attention (R15 measured form, 257us) with
// NON-TEMPORAL K/V loads. Block = (b, split of 32 tokens); 512 threads =
// 16 half-waves = 16 heads; block's combined K (and V) access per token is
// one contiguous 8KB row. Each (b,h,split) partial owned by ONE half-wave.
// ---------------------------------------------------------------------------
__global__ __launch_bounds__(512) void attn_partial_kernel(
    const float* __restrict__ q, const float* __restrict__ kv,
    const int* __restrict__ block_tables, const int* __restrict__ context_lens,
    const float* __restrict__ c4f, const float* __restrict__ s4f,
    float* __restrict__ pm, float* __restrict__ pl, float* __restrict__ pacc) {
    const int idx = blockIdx.x;              // b*64 + split
    const int split = idx & (NSPLIT2 - 1);
    const int b = idx >> 6;
    const int tid = threadIdx.x;
    const int h = tid >> 5;                  // half-wave id = head 0..15
    const int l5 = tid & 31;

    const int ctx = context_lens[b];
    const int s_begin = split * TOKSPL;
    const int len = min(TOKSPL, ctx - s_begin);

    // two block-table entries for this 32-token split (uniform scalar loads)
    const int bt0 = block_tables[b * NBLK + split * 2];
    const int bt1 = block_tables[b * NBLK + split * 2 + 1];

    const int out_idx = (b * HEADS + h) * NSPLIT2 + split;

    const float4 qr = *reinterpret_cast<const float4*>(q + b * HID + h * DHEAD + 4 * l5);
    const float sgn2 = (l5 & 16) ? -1.f : 1.f;
    const int fq4 = (l5 & 15) * 4;
    float4 pqs;   // partner of qr, pre-scaled by sgn2 (loop-invariant)
    pqs.x = sgn2 * __shfl_xor(qr.x, 16); pqs.y = sgn2 * __shfl_xor(qr.y, 16);
    pqs.z = sgn2 * __shfl_xor(qr.z, 16); pqs.w = sgn2 * __shfl_xor(qr.w, 16);

    float m = -INFINITY, l = 0.f;
    float4 a4 = make_float4(0.f, 0.f, 0.f, 0.f);

    if (len > 0) {
        const int NI = (len + 3) & ~3;

        #define LOADT(T, K4, V4, C4, S4) {                                         \
            int tc = min((T), len - 1);                                            \
            int blk = (tc & 16) ? bt1 : bt0;                                       \
            const float* kp = kv + (size_t)blk * 65536                             \
                                 + (size_t)(tc & 15) * 2048 + h * DHEAD;           \
            K4 = __builtin_nontemporal_load(reinterpret_cast<const floatx4*>(kp + 4 * l5)); \
            V4 = __builtin_nontemporal_load(reinterpret_cast<const floatx4*>(kp + 32768 + 4 * l5)); \
            C4 = *reinterpret_cast<const float4*>(c4f + (size_t)(s_begin + tc) * 64 + fq4); \
            S4 = *reinterpret_cast<const float4*>(s4f + (size_t)(s_begin + tc) * 64 + fq4); \
        }

        #define PROCT(T, K4, V4, C4, S4) {                                         \
            float cfx = fmaf(pqs.x, S4.x, qr.x * C4.x);                            \
            float cfy = fmaf(pqs.y, S4.y, qr.y * C4.y);                            \
            float cfz = fmaf(pqs.z, S4.z, qr.z * C4.z);                            \
            float cfw = fmaf(pqs.w, S4.w, qr.w * C4.w);                            \
            float dot = fmaf(K4[0], cfx, fmaf(K4[1], cfy, fmaf(K4[2], cfz, K4[3] * cfw))); \
            dot += __shfl_xor(dot, 1);  dot += __shfl_xor(dot, 2);                 \
            dot += __shfl_xor(dot, 4);  dot += __shfl_xor(dot, 8);                 \
            dot += __shfl_xor(dot, 16);                                            \
            float d = ((T) < len) ? dot * 0.08838834764831845f : -INFINITY;        \
            float mn = fmaxf(m, d);                                                \
            float ms = fmaxf(mn, -3.0e38f);                                        \
            float corr = __expf(m - ms);                                           \
            float e = __expf(d - ms);                                              \
            l = l * corr + e;                                                      \
            a4.x = fmaf(e, V4[0], a4.x * corr);                                    \
            a4.y = fmaf(e, V4[1], a4.y * corr);                                    \
            a4.z = fmaf(e, V4[2], a4.z * corr);                                    \
            a4.w = fmaf(e, V4[3], a4.w * corr);                                    \
            m = mn;                                                                \
        }

        floatx4 kA, vA, kB, vB, kC, vC, kD, vD;
        float4 cA, sA, cB, sB, cC, sC, cD, sD;
        LOADT(0, kA, vA, cA, sA);
        LOADT(1, kB, vB, cB, sB);
        LOADT(2, kC, vC, cC, sC);
        LOADT(3, kD, vD, cD, sD);

        for (int t = 0; t < NI; t += 4) {
            PROCT(t,     kA, vA, cA, sA);  LOADT(t + 4, kA, vA, cA, sA);
            PROCT(t + 1, kB, vB, cB, sB);  LOADT(t + 5, kB, vB, cB, sB);
            PROCT(t + 2, kC, vC, cC, sC);  LOADT(t + 6, kC, vC, cC, sC);
            PROCT(t + 3, kD, vD, cD, sD);  LOADT(t + 7, kD, vD, cD, sD);
        }
        #undef LOADT
        #undef PROCT
    }

    if (l5 == 0) { pm[out_idx] = m; pl[out_idx] = l; }
    *reinterpret_cast<float4*>(pacc + (size_t)out_idx * 128 + 4 * l5) = a4;
}

// ---------------------------------------------------------------------------
// Combine NSPLIT2 partials per (b,h).
// ---------------------------------------------------------------------------
__global__ void attn_combine_kernel(const float* __restrict__ pm, const float* __restrict__ pl,
                                    const float* __restrict__ pacc, float* __restrict__ attn_out) {
    const int bh = blockIdx.x;         // 512 blocks
    const int l5 = threadIdx.x;
    if (l5 >= 32) return;
    const int base = bh * NSPLIT2;
    float M = -INFINITY;
    for (int sp = 0; sp < NSPLIT2; ++sp) M = fmaxf(M, pm[base + sp]);
    float L = 0.f;
    float4 o = make_float4(0.f, 0.f, 0.f, 0.f);
    for (int sp = 0; sp < NSPLIT2; ++sp) {
        float mv = pm[base + sp];
        float ew = (mv == -INFINITY) ? 0.f : __expf(mv - M);
        L += pl[base + sp] * ew;
        float4 v = *reinterpret_cast<const float4*>(pacc + (size_t)(base + sp) * 128 + 4 * l5);
        o.x = fmaf(v.x, ew, o.x); o.y = fmaf(v.y, ew, o.y);
        o.z = fmaf(v.z, ew, o.z); o.w = fmaf(v.w, ew, o.w);
    }
    float inv = 1.f / L;
    *reinterpret_cast<float4*>(attn_out + bh * 128 + 4 * l5) =
        make_float4(o.x * inv, o.y * inv, o.z * inv, o.w * inv);
}

// ---------------------------------------------------------------------------
extern "C" void kernel_launch(void* const* d_in, const int* in_sizes, int n_in,
                              void* d_out, int out_size, void* d_ws, size_t ws_size,
                              hipStream_t stream) {
    const int*   input_ids    = (const int*)d_in[0];
    const int*   positions    = (const int*)d_in[1];
    const float* kv_cache     = (const float*)d_in[2];
    const int*   block_tables = (const int*)d_in[3];
    const int*   context_lens = (const int*)d_in[4];
    const float* embed_tokens = (const float*)d_in[5];
    const float* embed_pos    = (const float*)d_in[6];
    const float* Wq  = (const float*)d_in[7];
    const float* Wo  = (const float*)d_in[8];
    const float* Wprm= (const float*)d_in[9];
    const float* W1  = (const float*)d_in[10];
    const float* W2  = (const float*)d_in[11];
    float* out = (float*)d_out;

    char* ws = (char*)d_ws;
    size_t off = 0;
    float* c4f  = (float*)(ws + off); off += (size_t)KV_LEN * 64 * 4;     // 512 KB
    float* s4f  = (float*)(ws + off); off += (size_t)KV_LEN * 64 * 4;     // 512 KB
    float* emb  = (float*)(ws + off); off += (size_t)BATCH * HID * 4;     // 256 KB
    float* qbuf = (float*)(ws + off); off += (size_t)BATCH * HID * 4;
    float* attn = (float*)(ws + off); off += (size_t)BATCH * HID * 4;
    float* ao   = (float*)(ws + off); off += (size_t)BATCH * HID * 4;
    float* h1   = (float*)(ws + off); off += (size_t)BATCH * FFN * 4;     // 1 MB
    float* pm   = (float*)(ws + off); off += (size_t)BATCH * HEADS * NSPLIT2 * 4;
    float* plv  = (float*)(ws + off); off += (size_t)BATCH * HEADS * NSPLIT2 * 4;
    float* pacc = (float*)(ws + off); off += (size_t)BATCH * HEADS * NSPLIT2 * 128 * 4; // 16.8 MB
    float* S    = (float*)(ws + off); off += (size_t)16 * BATCH * HID * 4;  // 4.2 MB
    float* P    = (float*)(ws + off); off += (size_t)64 * BATCH * FFN * 4;  // max partials
    float* Pprm = (float*)(ws + off); off += (size_t)64 * BATCH * HID * 4;  // 16.8 MB
    (void)ws_size; (void)in_sizes; (void)n_in; (void)out_size;

    const int T4_HID = BATCH * HID / 4;   // 16384
    const int T4_FFN = BATCH * FFN / 4;   // 65536

    // 1. RoPE tables + embeddings
    prep_kernel<<<544, 256, 0, stream>>>(input_ids, positions, embed_tokens, embed_pos,
                                         c4f, s4f, emb);
    // 2. q = emb @ Wq  (Nsplit=4, SK=64, KC=32) -> 2-stage reduce + RoPE
    gemm2_kernel<32><<<dim3(4, 64), 256, 0, stream>>>(emb, Wq, P, HID, HID);
    red_stage1<<<dim3(64, 8), 256, 0, stream>>>(P, P, 8, S, T4_HID);
    rope_q_from_S<<<128, 256, 0, stream>>>(S, 8, positions, c4f, s4f, qbuf);
    // 3. head-cooperative paged attention (64 splits x 32 tokens) + combine
    attn_partial_kernel<<<BATCH * NSPLIT2, 512, 0, stream>>>(
        qbuf, kv_cache, block_tables, context_lens, c4f, s4f, pm, plv, pacc);
    attn_combine_kernel<<<BATCH * HEADS, 64, 0, stream>>>(pm, plv, pacc, attn);
    // 4. ao = attn @ Wo  (Nsplit=4, SK=64)
    gemm2_kernel<32><<<dim3(4, 64), 256, 0, stream>>>(attn, Wo, P, HID, HID);
    red_stage1<<<dim3(64, 8), 256, 0, stream>>>(P, P, 8, S, T4_HID);
    red_stage2<<<64, 256, 0, stream>>>(S, 8, T4_HID, ao);
    // 5. Pprm = ao @ Wprm  ||  P = ao @ W1   (one 512-block launch)
    gemm2_dual_kernel<<<512, 256, 0, stream>>>(ao, Wprm, W1, Pprm, P);
    // 6. h1 = reduce16(P)  (SK=16, 256-block single stage)
    reduce4_kernel<<<256, 256, 0, stream>>>(P, 16, T4_FFN, h1);
    // 7. out = h1 @ W2 + prm  (Nsplit=4, SK=64, KC=128; shared 2-stage reduce)
    gemm2_kernel<128><<<dim3(4, 64), 256, 0, stream>>>(h1, W2, P, FFN, HID);
    red_stage1<<<dim3(64, 16), 256, 0, stream>>>(P, Pprm, 8, S, T4_HID);
    red_stage2<<<64, 256, 0, stream>>>(S, 16, T4_HID, out);
}

// Round 17
// 271.823 us; speedup vs baseline: 1.1051x; 1.1051x over previous
//
#include <hip/hip_runtime.h>
#include <hip/hip_bf16.h>
#include <math.h>

// Problem constants (from reference)
#define BATCH   32
#define NBLK    128
#define BLOCK_T 16
#define HEADS   16
#define DHEAD   128
#define HID     2048
#define FFN     8192
#define KV_LEN  2048

#define NSPLIT2 64            // splits per sequence (32 tokens each)
#define TOKSPL  32            // tokens per split

typedef float floatx4 __attribute__((ext_vector_type(4)));   // builtin-compatible
typedef float floatx2 __attribute__((ext_vector_type(2)));

// ---------------------------------------------------------------------------
// prep: RoPE cos/sin tables ([tok][64] freq-major) + embeddings
// ---------------------------------------------------------------------------
__global__ void prep_kernel(const int* __restrict__ ids, const int* __restrict__ pos,
                            const float* __restrict__ et, const float* __restrict__ ep,
                            float* __restrict__ c4f, float* __restrict__ s4f,
                            float* __restrict__ emb) {
    if (blockIdx.x < 512) {
        int s = blockIdx.x * 4 + (threadIdx.x >> 6);   // 0..2047
        int i = threadIdx.x & 63;
        float inv = powf(10000.0f, -(float)i / 64.0f);
        float ang = (float)s * inv;
        c4f[s * 64 + i] = cosf(ang);
        s4f[s * 64 + i] = sinf(ang);
    } else {
        int b = blockIdx.x - 512;
        int id = ids[b], p = pos[b];
        const float4* a = (const float4*)(et + (size_t)id * HID);
        const float4* d = (const float4*)(ep + (size_t)p * HID);
        float4* o = (float4*)(emb + (size_t)b * HID);
        for (int c = threadIdx.x; c < HID / 4; c += 256) {
            float4 x = a[c], y = d[c];
            o[c] = make_float4(x.x + y.x, x.y + y.y, x.z + y.z, x.w + y.w);
        }
    }
}

// ---------------------------------------------------------------------------
// Split-K skinny GEMM body: X[32][K] @ W[K][N] -> P[chunk][32][N] partials.
// Thread: 2 consecutive cols, all 32 batch rows. W rows are a single-use
// stream with NO later consumer -> NON-TEMPORAL loads. P partials are
// producer->consumer traffic -> NORMAL (cached) stores, so the reduce reads
// hit L2/L3. 16-deep double-buffered prefetch. 512 cols per block.
// ---------------------------------------------------------------------------
template <int KC>
__device__ __forceinline__ void gemm2_body(
    const float* __restrict__ X, const float* __restrict__ W,
    float* __restrict__ P, int K, int N, int bx, int by, int tid) {
    __shared__ float xs[KC][36];
    const int k0 = by * KC;
    const int j  = bx * 512 + tid * 2;

    #pragma unroll
    for (int t = tid; t < 32 * KC / 4; t += 256) {
        int bb = t / (KC / 4), qq = t % (KC / 4);
        float4 xv = *reinterpret_cast<const float4*>(X + (size_t)bb * K + k0 + 4 * qq);
        xs[4 * qq + 0][bb] = xv.x; xs[4 * qq + 1][bb] = xv.y;
        xs[4 * qq + 2][bb] = xv.z; xs[4 * qq + 3][bb] = xv.w;
    }
    __syncthreads();

    float acc[32][2];
    #pragma unroll
    for (int bb = 0; bb < 32; ++bb) { acc[bb][0] = 0.f; acc[bb][1] = 0.f; }

    const float* wp = W + (size_t)k0 * N + j;
    floatx2 bufA[16], bufB[16];
    #pragma unroll
    for (int u = 0; u < 16; ++u)
        bufA[u] = __builtin_nontemporal_load(reinterpret_cast<const floatx2*>(wp + (size_t)u * N));

    #define G2_FMA16(BUF, KK)                                                   \
        _Pragma("unroll")                                                       \
        for (int u = 0; u < 16; ++u) {                                          \
            const floatx2 w = BUF[u];                                           \
            _Pragma("unroll")                                                   \
            for (int g = 0; g < 8; ++g) {                                       \
                const float4 xv = *reinterpret_cast<const float4*>(&xs[(KK) + u][g * 4]); \
                acc[4*g+0][0] = fmaf(xv.x, w[0], acc[4*g+0][0]);                \
                acc[4*g+0][1] = fmaf(xv.x, w[1], acc[4*g+0][1]);                \
                acc[4*g+1][0] = fmaf(xv.y, w[0], acc[4*g+1][0]);                \
                acc[4*g+1][1] = fmaf(xv.y, w[1], acc[4*g+1][1]);                \
                acc[4*g+2][0] = fmaf(xv.z, w[0], acc[4*g+2][0]);                \
                acc[4*g+2][1] = fmaf(xv.z, w[1], acc[4*g+2][1]);                \
                acc[4*g+3][0] = fmaf(xv.w, w[0], acc[4*g+3][0]);                \
                acc[4*g+3][1] = fmaf(xv.w, w[1], acc[4*g+3][1]);                \
            }                                                                   \
        }

    for (int kk = 0; kk < KC; kk += 32) {
        #pragma unroll
        for (int u = 0; u < 16; ++u)
            bufB[u] = __builtin_nontemporal_load(
                reinterpret_cast<const floatx2*>(wp + (size_t)(kk + 16 + u) * N));
        G2_FMA16(bufA, kk)
        #pragma unroll
        for (int u = 0; u < 16; ++u) {
            int rr = kk + 32 + u; rr = (rr < KC) ? rr : (KC - 1);
            bufA[u] = __builtin_nontemporal_load(
                reinterpret_cast<const floatx2*>(wp + (size_t)rr * N));
        }
        G2_FMA16(bufB, kk + 16)
    }
    #undef G2_FMA16

    float* pp = P + ((size_t)by * 32) * N + j;
    #pragma unroll
    for (int bb = 0; bb < 32; ++bb)
        *reinterpret_cast<float2*>(pp + (size_t)bb * N) = make_float2(acc[bb][0], acc[bb][1]);
}

template <int KC>
__global__ __launch_bounds__(256) void gemm2_kernel(
    const float* __restrict__ X, const float* __restrict__ W,
    float* __restrict__ P, int K, int N) {
    gemm2_body<KC>(X, W, P, K, N, blockIdx.x, blockIdx.y, threadIdx.x);
}

// merged: blocks 0..255 -> ao@Wprm (Nsplit=4, SK=64); 256..511 -> ao@W1 (Nsplit=16, SK=16)
__global__ __launch_bounds__(256) void gemm2_dual_kernel(
    const float* __restrict__ X, const float* __restrict__ Wprm,
    const float* __restrict__ W1,
    float* __restrict__ Pprm, float* __restrict__ P1) {
    if (blockIdx.x < 256) {
        gemm2_body<32>(X, Wprm, Pprm, HID, HID, blockIdx.x & 3, blockIdx.x >> 2, threadIdx.x);
    } else {
        int bb = blockIdx.x - 256;
        gemm2_body<128>(X, W1, P1, HID, FFN, bb & 15, bb >> 4, threadIdx.x);
    }
}

// ---------------------------------------------------------------------------
// stage1 partial reduction: group g sums 8 chunks -> S[g][total4]
// ---------------------------------------------------------------------------
__global__ void red_stage1(const float* __restrict__ PA, const float* __restrict__ PB,
                           int ngA, float* __restrict__ S, int total4) {
    int idx4 = blockIdx.x * 256 + threadIdx.x;
    if (idx4 >= total4) return;
    int g = blockIdx.y;
    const float4* src = (const float4*)((g < ngA) ? PA : PB);
    int c0 = ((g < ngA) ? g : (g - ngA)) * 8;
    float4 s = make_float4(0.f, 0.f, 0.f, 0.f);
    #pragma unroll
    for (int c = 0; c < 8; ++c) {
        float4 v = src[(size_t)(c0 + c) * total4 + idx4];
        s.x += v.x; s.y += v.y; s.z += v.z; s.w += v.w;
    }
    ((float4*)S)[(size_t)g * total4 + idx4] = s;
}

__global__ void red_stage2(const float* __restrict__ S, int ng, int total4,
                           float* __restrict__ out) {
    int idx4 = blockIdx.x * 256 + threadIdx.x;
    if (idx4 >= total4) return;
    float4 s = make_float4(0.f, 0.f, 0.f, 0.f);
    for (int g = 0; g < ng; ++g) {
        float4 v = ((const float4*)S)[(size_t)g * total4 + idx4];
        s.x += v.x; s.y += v.y; s.z += v.z; s.w += v.w;
    }
    ((float4*)out)[idx4] = s;
}

// single-stage reduce (few chunks): out[idx4] = sum_c P[c][idx4]
__global__ void reduce4_kernel(const float* __restrict__ P, int nch, int total4,
                               float* __restrict__ out) {
    int idx4 = blockIdx.x * 256 + threadIdx.x;
    if (idx4 >= total4) return;
    const float4* P4 = (const float4*)P;
    float4 s = make_float4(0.f, 0.f, 0.f, 0.f);
    for (int c = 0; c < nch; ++c) {
        float4 v = P4[(size_t)c * total4 + idx4];
        s.x += v.x; s.y += v.y; s.z += v.z; s.w += v.w;
    }
    ((float4*)out)[idx4] = s;
}

// ---------------------------------------------------------------------------
// Final Wq reduce (from S groups) + RoPE -> q[32][2048]
// ---------------------------------------------------------------------------
__global__ void rope_q_from_S(const float* __restrict__ S, int ng,
                              const int* __restrict__ positions,
                              const float* __restrict__ c4f, const float* __restrict__ s4f,
                              float* __restrict__ qout) {
    int idx = blockIdx.x * 256 + threadIdx.x;   // 32768 threads
    int i = idx & 63, hh = (idx >> 6) & 15, b = idx >> 10;
    int base = b * HID + hh * DHEAD;
    float q1 = 0.f, q2 = 0.f;
    for (int g = 0; g < ng; ++g) {
        q1 += S[(size_t)g * (BATCH * HID) + base + i];
        q2 += S[(size_t)g * (BATCH * HID) + base + 64 + i];
    }
    int pos = positions[b];
    float co = c4f[pos * 64 + i], si = s4f[pos * 64 + i];
    qout[base + i]      = q1 * co - q2 * si;
    qout[base + 64 + i] = q1 * si + q2 * co;
}

// ---------------------------------------------------------------------------
// Head-cooperative flash-decode attention (R15 measured form, 257us) with
// NON-TEMPORAL K/V loads. Block = (b, split of 32 tokens); 512 threads =
// 16 half-waves = 16 heads; block's combined K (and V) access per token is
// one contiguous 8KB row. Each (b,h,split) partial owned by ONE half-wave.
// ---------------------------------------------------------------------------
__global__ __launch_bounds__(512) void attn_partial_kernel(
    const float* __restrict__ q, const float* __restrict__ kv,
    const int* __restrict__ block_tables, const int* __restrict__ context_lens,
    const float* __restrict__ c4f, const float* __restrict__ s4f,
    float* __restrict__ pm, float* __restrict__ pl, float* __restrict__ pacc) {
    const int idx = blockIdx.x;              // b*64 + split
    const int split = idx & (NSPLIT2 - 1);
    const int b = idx >> 6;
    const int tid = threadIdx.x;
    const int h = tid >> 5;                  // half-wave id = head 0..15
    const int l5 = tid & 31;

    const int ctx = context_lens[b];
    const int s_begin = split * TOKSPL;
    const int len = min(TOKSPL, ctx - s_begin);

    // two block-table entries for this 32-token split (uniform scalar loads)
    const int bt0 = block_tables[b * NBLK + split * 2];
    const int bt1 = block_tables[b * NBLK + split * 2 + 1];

    const int out_idx = (b * HEADS + h) * NSPLIT2 + split;

    const float4 qr = *reinterpret_cast<const float4*>(q + b * HID + h * DHEAD + 4 * l5);
    const float sgn2 = (l5 & 16) ? -1.f : 1.f;
    const int fq4 = (l5 & 15) * 4;
    float4 pqs;   // partner of qr, pre-scaled by sgn2 (loop-invariant)
    pqs.x = sgn2 * __shfl_xor(qr.x, 16); pqs.y = sgn2 * __shfl_xor(qr.y, 16);
    pqs.z = sgn2 * __shfl_xor(qr.z, 16); pqs.w = sgn2 * __shfl_xor(qr.w, 16);

    float m = -INFINITY, l = 0.f;
    float4 a4 = make_float4(0.f, 0.f, 0.f, 0.f);

    if (len > 0) {
        const int NI = (len + 3) & ~3;

        #define LOADT(T, K4, V4, C4, S4) {                                         \
            int tc = min((T), len - 1);                                            \
            int blk = (tc & 16) ? bt1 : bt0;                                       \
            const float* kp = kv + (size_t)blk * 65536                             \
                                 + (size_t)(tc & 15) * 2048 + h * DHEAD;           \
            K4 = __builtin_nontemporal_load(reinterpret_cast<const floatx4*>(kp + 4 * l5)); \
            V4 = __builtin_nontemporal_load(reinterpret_cast<const floatx4*>(kp + 32768 + 4 * l5)); \
            C4 = *reinterpret_cast<const float4*>(c4f + (size_t)(s_begin + tc) * 64 + fq4); \
            S4 = *reinterpret_cast<const float4*>(s4f + (size_t)(s_begin + tc) * 64 + fq4); \
        }

        #define PROCT(T, K4, V4, C4, S4) {                                         \
            float cfx = fmaf(pqs.x, S4.x, qr.x * C4.x);                            \
            float cfy = fmaf(pqs.y, S4.y, qr.y * C4.y);                            \
            float cfz = fmaf(pqs.z, S4.z, qr.z * C4.z);                            \
            float cfw = fmaf(pqs.w, S4.w, qr.w * C4.w);                            \
            float dot = fmaf(K4[0], cfx, fmaf(K4[1], cfy, fmaf(K4[2], cfz, K4[3] * cfw))); \
            dot += __shfl_xor(dot, 1);  dot += __shfl_xor(dot, 2);                 \
            dot += __shfl_xor(dot, 4);  dot += __shfl_xor(dot, 8);                 \
            dot += __shfl_xor(dot, 16);                                            \
            float d = ((T) < len) ? dot * 0.08838834764831845f : -INFINITY;        \
            float mn = fmaxf(m, d);                                                \
            float ms = fmaxf(mn, -3.0e38f);                                        \
            float corr = __expf(m - ms);                                           \
            float e = __expf(d - ms);                                              \
            l = l * corr + e;                                                      \
            a4.x = fmaf(e, V4[0], a4.x * corr);                                    \
            a4.y = fmaf(e, V4[1], a4.y * corr);                                    \
            a4.z = fmaf(e, V4[2], a4.z * corr);                                    \
            a4.w = fmaf(e, V4[3], a4.w * corr);                                    \
            m = mn;                                                                \
        }

        floatx4 kA, vA, kB, vB, kC, vC, kD, vD;
        float4 cA, sA, cB, sB, cC, sC, cD, sD;
        LOADT(0, kA, vA, cA, sA);
        LOADT(1, kB, vB, cB, sB);
        LOADT(2, kC, vC, cC, sC);
        LOADT(3, kD, vD, cD, sD);

        for (int t = 0; t < NI; t += 4) {
            PROCT(t,     kA, vA, cA, sA);  LOADT(t + 4, kA, vA, cA, sA);
            PROCT(t + 1, kB, vB, cB, sB);  LOADT(t + 5, kB, vB, cB, sB);
            PROCT(t + 2, kC, vC, cC, sC);  LOADT(t + 6, kC, vC, cC, sC);
            PROCT(t + 3, kD, vD, cD, sD);  LOADT(t + 7, kD, vD, cD, sD);
        }
        #undef LOADT
        #undef PROCT
    }

    if (l5 == 0) { pm[out_idx] = m; pl[out_idx] = l; }
    *reinterpret_cast<float4*>(pacc + (size_t)out_idx * 128 + 4 * l5) = a4;
}

// ---------------------------------------------------------------------------
// Combine NSPLIT2 partials per (b,h).
// ---------------------------------------------------------------------------
__global__ void attn_combine_kernel(const float* __restrict__ pm, const float* __restrict__ pl,
                                    const float* __restrict__ pacc, float* __restrict__ attn_out) {
    const int bh = blockIdx.x;         // 512 blocks
    const int l5 = threadIdx.x;
    if (l5 >= 32) return;
    const int base = bh * NSPLIT2;
    float M = -INFINITY;
    for (int sp = 0; sp < NSPLIT2; ++sp) M = fmaxf(M, pm[base + sp]);
    float L = 0.f;
    float4 o = make_float4(0.f, 0.f, 0.f, 0.f);
    for (int sp = 0; sp < NSPLIT2; ++sp) {
        float mv = pm[base + sp];
        float ew = (mv == -INFINITY) ? 0.f : __expf(mv - M);
        L += pl[base + sp] * ew;
        float4 v = *reinterpret_cast<const float4*>(pacc + (size_t)(base + sp) * 128 + 4 * l5);
        o.x = fmaf(v.x, ew, o.x); o.y = fmaf(v.y, ew, o.y);
        o.z = fmaf(v.z, ew, o.z); o.w = fmaf(v.w, ew, o.w);
    }
    float inv = 1.f / L;
    *reinterpret_cast<float4*>(attn_out + bh * 128 + 4 * l5) =
        make_float4(o.x * inv, o.y * inv, o.z * inv, o.w * inv);
}

// ---------------------------------------------------------------------------
extern "C" void kernel_launch(void* const* d_in, const int* in_sizes, int n_in,
                              void* d_out, int out_size, void* d_ws, size_t ws_size,
                              hipStream_t stream) {
    const int*   input_ids    = (const int*)d_in[0];
    const int*   positions    = (const int*)d_in[1];
    const float* kv_cache     = (const float*)d_in[2];
    const int*   block_tables = (const int*)d_in[3];
    const int*   context_lens = (const int*)d_in[4];
    const float* embed_tokens = (const float*)d_in[5];
    const float* embed_pos    = (const float*)d_in[6];
    const float* Wq  = (const float*)d_in[7];
    const float* Wo  = (const float*)d_in[8];
    const float* Wprm= (const float*)d_in[9];
    const float* W1  = (const float*)d_in[10];
    const float* W2  = (const float*)d_in[11];
    float* out = (float*)d_out;

    char* ws = (char*)d_ws;
    size_t off = 0;
    float* c4f  = (float*)(ws + off); off += (size_t)KV_LEN * 64 * 4;     // 512 KB
    float* s4f  = (float*)(ws + off); off += (size_t)KV_LEN * 64 * 4;     // 512 KB
    float* emb  = (float*)(ws + off); off += (size_t)BATCH * HID * 4;     // 256 KB
    float* qbuf = (float*)(ws + off); off += (size_t)BATCH * HID * 4;
    float* attn = (float*)(ws + off); off += (size_t)BATCH * HID * 4;
    float* ao   = (float*)(ws + off); off += (size_t)BATCH * HID * 4;
    float* h1   = (float*)(ws + off); off += (size_t)BATCH * FFN * 4;     // 1 MB
    float* pm   = (float*)(ws + off); off += (size_t)BATCH * HEADS * NSPLIT2 * 4;
    float* plv  = (float*)(ws + off); off += (size_t)BATCH * HEADS * NSPLIT2 * 4;
    float* pacc = (float*)(ws + off); off += (size_t)BATCH * HEADS * NSPLIT2 * 128 * 4; // 16.8 MB
    float* S    = (float*)(ws + off); off += (size_t)16 * BATCH * HID * 4;  // 4.2 MB
    float* P    = (float*)(ws + off); off += (size_t)64 * BATCH * FFN * 4;  // max partials
    float* Pprm = (float*)(ws + off); off += (size_t)64 * BATCH * HID * 4;  // 16.8 MB
    (void)ws_size; (void)in_sizes; (void)n_in; (void)out_size;

    const int T4_HID = BATCH * HID / 4;   // 16384
    const int T4_FFN = BATCH * FFN / 4;   // 65536

    // 1. RoPE tables + embeddings
    prep_kernel<<<544, 256, 0, stream>>>(input_ids, positions, embed_tokens, embed_pos,
                                         c4f, s4f, emb);
    // 2. q = emb @ Wq  (Nsplit=4, SK=64, KC=32) -> 2-stage reduce + RoPE
    gemm2_kernel<32><<<dim3(4, 64), 256, 0, stream>>>(emb, Wq, P, HID, HID);
    red_stage1<<<dim3(64, 8), 256, 0, stream>>>(P, P, 8, S, T4_HID);
    rope_q_from_S<<<128, 256, 0, stream>>>(S, 8, positions, c4f, s4f, qbuf);
    // 3. head-cooperative paged attention (64 splits x 32 tokens) + combine
    attn_partial_kernel<<<BATCH * NSPLIT2, 512, 0, stream>>>(
        qbuf, kv_cache, block_tables, context_lens, c4f, s4f, pm, plv, pacc);
    attn_combine_kernel<<<BATCH * HEADS, 64, 0, stream>>>(pm, plv, pacc, attn);
    // 4. ao = attn @ Wo  (Nsplit=4, SK=64)
    gemm2_kernel<32><<<dim3(4, 64), 256, 0, stream>>>(attn, Wo, P, HID, HID);
    red_stage1<<<dim3(64, 8), 256, 0, stream>>>(P, P, 8, S, T4_HID);
    red_stage2<<<64, 256, 0, stream>>>(S, 8, T4_HID, ao);
    // 5. Pprm = ao @ Wprm  ||  P = ao @ W1   (one 512-block launch)
    gemm2_dual_kernel<<<512, 256, 0, stream>>>(ao, Wprm, W1, Pprm, P);
    // 6. h1 = reduce16(P)  (SK=16, 256-block single stage)
    reduce4_kernel<<<256, 256, 0, stream>>>(P, 16, T4_FFN, h1);
    // 7. out = h1 @ W2 + prm  (Nsplit=4, SK=64, KC=128; shared 2-stage reduce)
    gemm2_kernel<128><<<dim3(4, 64), 256, 0, stream>>>(h1, W2, P, FFN, HID);
    red_stage1<<<dim3(64, 16), 256, 0, stream>>>(P, Pprm, 8, S, T4_HID);
    red_stage2<<<64, 256, 0, stream>>>(S, 16, T4_HID, out);
}

// Round 18
// 256.666 us; speedup vs baseline: 1.1704x; 1.0591x over previous
//
#include <hip/hip_runtime.h>
#include <hip/hip_bf16.h>
#include <math.h>

// Problem constants (from reference)
#define BATCH   32
#define NBLK    128
#define BLOCK_T 16
#define HEADS   16
#define DHEAD   128
#define HID     2048
#define FFN     8192
#define KV_LEN  2048

#define NSPLIT2 64            // splits per sequence (32 tokens each)
#define TOKSPL  32            // tokens per split

typedef float floatx4 __attribute__((ext_vector_type(4)));   // builtin-compatible

// ---------------------------------------------------------------------------
// prep: RoPE cos/sin tables ([tok][64] freq-major) + embeddings
// ---------------------------------------------------------------------------
__global__ void prep_kernel(const int* __restrict__ ids, const int* __restrict__ pos,
                            const float* __restrict__ et, const float* __restrict__ ep,
                            float* __restrict__ c4f, float* __restrict__ s4f,
                            float* __restrict__ emb) {
    if (blockIdx.x < 512) {
        int s = blockIdx.x * 4 + (threadIdx.x >> 6);   // 0..2047
        int i = threadIdx.x & 63;
        float inv = powf(10000.0f, -(float)i / 64.0f);
        float ang = (float)s * inv;
        c4f[s * 64 + i] = cosf(ang);
        s4f[s * 64 + i] = sinf(ang);
    } else {
        int b = blockIdx.x - 512;
        int id = ids[b], p = pos[b];
        const float4* a = (const float4*)(et + (size_t)id * HID);
        const float4* d = (const float4*)(ep + (size_t)p * HID);
        float4* o = (float4*)(emb + (size_t)b * HID);
        for (int c = threadIdx.x; c < HID / 4; c += 256) {
            float4 x = a[c], y = d[c];
            o[c] = make_float4(x.x + y.x, x.y + y.y, x.z + y.z, x.w + y.w);
        }
    }
}

// ---------------------------------------------------------------------------
// Split-K skinny GEMM body: X[32][K] @ W[K][N] -> P[chunk][32][N] partials.
// Thread: 2 consecutive cols (float2 W loads), all 32 batch rows.
// 16-deep double-buffered prefetch (8 KB/wave in flight). 512 cols per block.
// ---------------------------------------------------------------------------
template <int KC>
__device__ __forceinline__ void gemm2_body(
    const float* __restrict__ X, const float* __restrict__ W,
    float* __restrict__ P, int K, int N, int bx, int by, int tid) {
    __shared__ float xs[KC][36];
    const int k0 = by * KC;
    const int j  = bx * 512 + tid * 2;

    #pragma unroll
    for (int t = tid; t < 32 * KC / 4; t += 256) {
        int bb = t / (KC / 4), qq = t % (KC / 4);
        float4 xv = *reinterpret_cast<const float4*>(X + (size_t)bb * K + k0 + 4 * qq);
        xs[4 * qq + 0][bb] = xv.x; xs[4 * qq + 1][bb] = xv.y;
        xs[4 * qq + 2][bb] = xv.z; xs[4 * qq + 3][bb] = xv.w;
    }
    __syncthreads();

    float acc[32][2];
    #pragma unroll
    for (int bb = 0; bb < 32; ++bb) { acc[bb][0] = 0.f; acc[bb][1] = 0.f; }

    const float* wp = W + (size_t)k0 * N + j;
    float2 bufA[16], bufB[16];
    #pragma unroll
    for (int u = 0; u < 16; ++u)
        bufA[u] = *reinterpret_cast<const float2*>(wp + (size_t)u * N);

    #define G2_FMA16(BUF, KK)                                                   \
        _Pragma("unroll")                                                       \
        for (int u = 0; u < 16; ++u) {                                          \
            const float2 w = BUF[u];                                            \
            _Pragma("unroll")                                                   \
            for (int g = 0; g < 8; ++g) {                                       \
                const float4 xv = *reinterpret_cast<const float4*>(&xs[(KK) + u][g * 4]); \
                acc[4*g+0][0] = fmaf(xv.x, w.x, acc[4*g+0][0]);                 \
                acc[4*g+0][1] = fmaf(xv.x, w.y, acc[4*g+0][1]);                 \
                acc[4*g+1][0] = fmaf(xv.y, w.x, acc[4*g+1][0]);                 \
                acc[4*g+1][1] = fmaf(xv.y, w.y, acc[4*g+1][1]);                 \
                acc[4*g+2][0] = fmaf(xv.z, w.x, acc[4*g+2][0]);                 \
                acc[4*g+2][1] = fmaf(xv.z, w.y, acc[4*g+2][1]);                 \
                acc[4*g+3][0] = fmaf(xv.w, w.x, acc[4*g+3][0]);                 \
                acc[4*g+3][1] = fmaf(xv.w, w.y, acc[4*g+3][1]);                 \
            }                                                                   \
        }

    for (int kk = 0; kk < KC; kk += 32) {
        #pragma unroll
        for (int u = 0; u < 16; ++u)
            bufB[u] = *reinterpret_cast<const float2*>(wp + (size_t)(kk + 16 + u) * N);
        G2_FMA16(bufA, kk)
        #pragma unroll
        for (int u = 0; u < 16; ++u) {
            int rr = kk + 32 + u; rr = (rr < KC) ? rr : (KC - 1);
            bufA[u] = *reinterpret_cast<const float2*>(wp + (size_t)rr * N);
        }
        G2_FMA16(bufB, kk + 16)
    }
    #undef G2_FMA16

    float* pp = P + ((size_t)by * 32) * N + j;
    #pragma unroll
    for (int bb = 0; bb < 32; ++bb)
        *reinterpret_cast<float2*>(pp + (size_t)bb * N) = make_float2(acc[bb][0], acc[bb][1]);
}

template <int KC>
__global__ __launch_bounds__(256) void gemm2_kernel(
    const float* __restrict__ X, const float* __restrict__ W,
    float* __restrict__ P, int K, int N) {
    gemm2_body<KC>(X, W, P, K, N, blockIdx.x, blockIdx.y, threadIdx.x);
}

// merged: blocks 0..255 -> ao@Wprm (Nsplit=4, SK=64); 256..511 -> ao@W1 (Nsplit=16, SK=16)
__global__ __launch_bounds__(256) void gemm2_dual_kernel(
    const float* __restrict__ X, const float* __restrict__ Wprm,
    const float* __restrict__ W1,
    float* __restrict__ Pprm, float* __restrict__ P1) {
    if (blockIdx.x < 256) {
        gemm2_body<32>(X, Wprm, Pprm, HID, HID, blockIdx.x & 3, blockIdx.x >> 2, threadIdx.x);
    } else {
        int bb = blockIdx.x - 256;
        gemm2_body<128>(X, W1, P1, HID, FFN, bb & 15, bb >> 4, threadIdx.x);
    }
}

// ---------------------------------------------------------------------------
// stage1 partial reduction: group g sums 8 chunks -> S[g][total4]
// ---------------------------------------------------------------------------
__global__ void red_stage1(const float* __restrict__ PA, const float* __restrict__ PB,
                           int ngA, float* __restrict__ S, int total4) {
    int idx4 = blockIdx.x * 256 + threadIdx.x;
    if (idx4 >= total4) return;
    int g = blockIdx.y;
    const float4* src = (const float4*)((g < ngA) ? PA : PB);
    int c0 = ((g < ngA) ? g : (g - ngA)) * 8;
    float4 s = make_float4(0.f, 0.f, 0.f, 0.f);
    #pragma unroll
    for (int c = 0; c < 8; ++c) {
        float4 v = src[(size_t)(c0 + c) * total4 + idx4];
        s.x += v.x; s.y += v.y; s.z += v.z; s.w += v.w;
    }
    ((float4*)S)[(size_t)g * total4 + idx4] = s;
}

__global__ void red_stage2(const float* __restrict__ S, int ng, int total4,
                           float* __restrict__ out) {
    int idx4 = blockIdx.x * 256 + threadIdx.x;
    if (idx4 >= total4) return;
    float4 s = make_float4(0.f, 0.f, 0.f, 0.f);
    for (int g = 0; g < ng; ++g) {
        float4 v = ((const float4*)S)[(size_t)g * total4 + idx4];
        s.x += v.x; s.y += v.y; s.z += v.z; s.w += v.w;
    }
    ((float4*)out)[idx4] = s;
}

// single-stage reduce (few chunks): out[idx4] = sum_c P[c][idx4]
__global__ void reduce4_kernel(const float* __restrict__ P, int nch, int total4,
                               float* __restrict__ out) {
    int idx4 = blockIdx.x * 256 + threadIdx.x;
    if (idx4 >= total4) return;
    const float4* P4 = (const float4*)P;
    float4 s = make_float4(0.f, 0.f, 0.f, 0.f);
    for (int c = 0; c < nch; ++c) {
        float4 v = P4[(size_t)c * total4 + idx4];
        s.x += v.x; s.y += v.y; s.z += v.z; s.w += v.w;
    }
    ((float4*)out)[idx4] = s;
}

// ---------------------------------------------------------------------------
// Final Wq reduce (from S groups) + RoPE -> q[32][2048]
// ---------------------------------------------------------------------------
__global__ void rope_q_from_S(const float* __restrict__ S, int ng,
                              const int* __restrict__ positions,
                              const float* __restrict__ c4f, const float* __restrict__ s4f,
                              float* __restrict__ qout) {
    int idx = blockIdx.x * 256 + threadIdx.x;   // 32768 threads
    int i = idx & 63, hh = (idx >> 6) & 15, b = idx >> 10;
    int base = b * HID + hh * DHEAD;
    float q1 = 0.f, q2 = 0.f;
    for (int g = 0; g < ng; ++g) {
        q1 += S[(size_t)g * (BATCH * HID) + base + i];
        q2 += S[(size_t)g * (BATCH * HID) + base + 64 + i];
    }
    int pos = positions[b];
    float co = c4f[pos * 64 + i], si = s4f[pos * 64 + i];
    qout[base + i]      = q1 * co - q2 * si;
    qout[base + 64 + i] = q1 * si + q2 * co;
}

// ---------------------------------------------------------------------------
// Head-cooperative flash-decode attention (R15 measured form, 257us) with
// NON-TEMPORAL K/V loads. Block = (b, split of 32 tokens); 512 threads =
// 16 half-waves = 16 heads; block's combined K (and V) access per token is
// one contiguous 8KB row. Each (b,h,split) partial owned by ONE half-wave.
// ---------------------------------------------------------------------------
__global__ __launch_bounds__(512) void attn_partial_kernel(
    const float* __restrict__ q, const float* __restrict__ kv,
    const int* __restrict__ block_tables, const int* __restrict__ context_lens,
    const float* __restrict__ c4f, const float* __restrict__ s4f,
    float* __restrict__ pm, float* __restrict__ pl, float* __restrict__ pacc) {
    const int idx = blockIdx.x;              // b*64 + split
    const int split = idx & (NSPLIT2 - 1);
    const int b = idx >> 6;
    const int tid = threadIdx.x;
    const int h = tid >> 5;                  // half-wave id = head 0..15
    const int l5 = tid & 31;

    const int ctx = context_lens[b];
    const int s_begin = split * TOKSPL;
    const int len = min(TOKSPL, ctx - s_begin);

    // two block-table entries for this 32-token split (uniform scalar loads)
    const int bt0 = block_tables[b * NBLK + split * 2];
    const int bt1 = block_tables[b * NBLK + split * 2 + 1];

    const int out_idx = (b * HEADS + h) * NSPLIT2 + split;

    const float4 qr = *reinterpret_cast<const float4*>(q + b * HID + h * DHEAD + 4 * l5);
    const float sgn2 = (l5 & 16) ? -1.f : 1.f;
    const int fq4 = (l5 & 15) * 4;
    float4 pqs;   // partner of qr, pre-scaled by sgn2 (loop-invariant)
    pqs.x = sgn2 * __shfl_xor(qr.x, 16); pqs.y = sgn2 * __shfl_xor(qr.y, 16);
    pqs.z = sgn2 * __shfl_xor(qr.z, 16); pqs.w = sgn2 * __shfl_xor(qr.w, 16);

    float m = -INFINITY, l = 0.f;
    float4 a4 = make_float4(0.f, 0.f, 0.f, 0.f);

    if (len > 0) {
        const int NI = (len + 3) & ~3;

        #define LOADT(T, K4, V4, C4, S4) {                                         \
            int tc = min((T), len - 1);                                            \
            int blk = (tc & 16) ? bt1 : bt0;                                       \
            const float* kp = kv + (size_t)blk * 65536                             \
                                 + (size_t)(tc & 15) * 2048 + h * DHEAD;           \
            K4 = __builtin_nontemporal_load(reinterpret_cast<const floatx4*>(kp + 4 * l5)); \
            V4 = __builtin_nontemporal_load(reinterpret_cast<const floatx4*>(kp + 32768 + 4 * l5)); \
            C4 = *reinterpret_cast<const float4*>(c4f + (size_t)(s_begin + tc) * 64 + fq4); \
            S4 = *reinterpret_cast<const float4*>(s4f + (size_t)(s_begin + tc) * 64 + fq4); \
        }

        #define PROCT(T, K4, V4, C4, S4) {                                         \
            float cfx = fmaf(pqs.x, S4.x, qr.x * C4.x);                            \
            float cfy = fmaf(pqs.y, S4.y, qr.y * C4.y);                            \
            float cfz = fmaf(pqs.z, S4.z, qr.z * C4.z);                            \
            float cfw = fmaf(pqs.w, S4.w, qr.w * C4.w);                            \
            float dot = fmaf(K4[0], cfx, fmaf(K4[1], cfy, fmaf(K4[2], cfz, K4[3] * cfw))); \
            dot += __shfl_xor(dot, 1);  dot += __shfl_xor(dot, 2);                 \
            dot += __shfl_xor(dot, 4);  dot += __shfl_xor(dot, 8);                 \
            dot += __shfl_xor(dot, 16);                                            \
            float d = ((T) < len) ? dot * 0.08838834764831845f : -INFINITY;        \
            float mn = fmaxf(m, d);                                                \
            float ms = fmaxf(mn, -3.0e38f);                                        \
            float corr = __expf(m - ms);                                           \
            float e = __expf(d - ms);                                              \
            l = l * corr + e;                                                      \
            a4.x = fmaf(e, V4[0], a4.x * corr);                                    \
            a4.y = fmaf(e, V4[1], a4.y * corr);                                    \
            a4.z = fmaf(e, V4[2], a4.z * corr);                                    \
            a4.w = fmaf(e, V4[3], a4.w * corr);                                    \
            m = mn;                                                                \
        }

        floatx4 kA, vA, kB, vB, kC, vC, kD, vD;
        float4 cA, sA, cB, sB, cC, sC, cD, sD;
        LOADT(0, kA, vA, cA, sA);
        LOADT(1, kB, vB, cB, sB);
        LOADT(2, kC, vC, cC, sC);
        LOADT(3, kD, vD, cD, sD);

        for (int t = 0; t < NI; t += 4) {
            PROCT(t,     kA, vA, cA, sA);  LOADT(t + 4, kA, vA, cA, sA);
            PROCT(t + 1, kB, vB, cB, sB);  LOADT(t + 5, kB, vB, cB, sB);
            PROCT(t + 2, kC, vC, cC, sC);  LOADT(t + 6, kC, vC, cC, sC);
            PROCT(t + 3, kD, vD, cD, sD);  LOADT(t + 7, kD, vD, cD, sD);
        }
        #undef LOADT
        #undef PROCT
    }

    if (l5 == 0) { pm[out_idx] = m; pl[out_idx] = l; }
    *reinterpret_cast<float4*>(pacc + (size_t)out_idx * 128 + 4 * l5) = a4;
}

// ---------------------------------------------------------------------------
// Combine NSPLIT2 partials per (b,h).
// ---------------------------------------------------------------------------
__global__ void attn_combine_kernel(const float* __restrict__ pm, const float* __restrict__ pl,
                                    const float* __restrict__ pacc, float* __restrict__ attn_out) {
    const int bh = blockIdx.x;         // 512 blocks
    const int l5 = threadIdx.x;
    if (l5 >= 32) return;
    const int base = bh * NSPLIT2;
    float M = -INFINITY;
    for (int sp = 0; sp < NSPLIT2; ++sp) M = fmaxf(M, pm[base + sp]);
    float L = 0.f;
    float4 o = make_float4(0.f, 0.f, 0.f, 0.f);
    for (int sp = 0; sp < NSPLIT2; ++sp) {
        float mv = pm[base + sp];
        float ew = (mv == -INFINITY) ? 0.f : __expf(mv - M);
        L += pl[base + sp] * ew;
        float4 v = *reinterpret_cast<const float4*>(pacc + (size_t)(base + sp) * 128 + 4 * l5);
        o.x = fmaf(v.x, ew, o.x); o.y = fmaf(v.y, ew, o.y);
        o.z = fmaf(v.z, ew, o.z); o.w = fmaf(v.w, ew, o.w);
    }
    float inv = 1.f / L;
    *reinterpret_cast<float4*>(attn_out + bh * 128 + 4 * l5) =
        make_float4(o.x * inv, o.y * inv, o.z * inv, o.w * inv);
}

// ---------------------------------------------------------------------------
extern "C" void kernel_launch(void* const* d_in, const int* in_sizes, int n_in,
                              void* d_out, int out_size, void* d_ws, size_t ws_size,
                              hipStream_t stream) {
    const int*   input_ids    = (const int*)d_in[0];
    const int*   positions    = (const int*)d_in[1];
    const float* kv_cache     = (const float*)d_in[2];
    const int*   block_tables = (const int*)d_in[3];
    const int*   context_lens = (const int*)d_in[4];
    const float* embed_tokens = (const float*)d_in[5];
    const float* embed_pos    = (const float*)d_in[6];
    const float* Wq  = (const float*)d_in[7];
    const float* Wo  = (const float*)d_in[8];
    const float* Wprm= (const float*)d_in[9];
    const float* W1  = (const float*)d_in[10];
    const float* W2  = (const float*)d_in[11];
    float* out = (float*)d_out;

    char* ws = (char*)d_ws;
    size_t off = 0;
    float* c4f  = (float*)(ws + off); off += (size_t)KV_LEN * 64 * 4;     // 512 KB
    float* s4f  = (float*)(ws + off); off += (size_t)KV_LEN * 64 * 4;     // 512 KB
    float* emb  = (float*)(ws + off); off += (size_t)BATCH * HID * 4;     // 256 KB
    float* qbuf = (float*)(ws + off); off += (size_t)BATCH * HID * 4;
    float* attn = (float*)(ws + off); off += (size_t)BATCH * HID * 4;
    float* ao   = (float*)(ws + off); off += (size_t)BATCH * HID * 4;
    float* h1   = (float*)(ws + off); off += (size_t)BATCH * FFN * 4;     // 1 MB
    float* pm   = (float*)(ws + off); off += (size_t)BATCH * HEADS * NSPLIT2 * 4;
    float* plv  = (float*)(ws + off); off += (size_t)BATCH * HEADS * NSPLIT2 * 4;
    float* pacc = (float*)(ws + off); off += (size_t)BATCH * HEADS * NSPLIT2 * 128 * 4; // 16.8 MB
    float* S    = (float*)(ws + off); off += (size_t)16 * BATCH * HID * 4;  // 4.2 MB
    float* P    = (float*)(ws + off); off += (size_t)64 * BATCH * FFN * 4;  // max partials
    float* Pprm = (float*)(ws + off); off += (size_t)64 * BATCH * HID * 4;  // 16.8 MB
    (void)ws_size; (void)in_sizes; (void)n_in; (void)out_size;

    const int T4_HID = BATCH * HID / 4;   // 16384
    const int T4_FFN = BATCH * FFN / 4;   // 65536

    // 1. RoPE tables + embeddings
    prep_kernel<<<544, 256, 0, stream>>>(input_ids, positions, embed_tokens, embed_pos,
                                         c4f, s4f, emb);
    // 2. q = emb @ Wq  (Nsplit=4, SK=64, KC=32) -> 2-stage reduce + RoPE
    gemm2_kernel<32><<<dim3(4, 64), 256, 0, stream>>>(emb, Wq, P, HID, HID);
    red_stage1<<<dim3(64, 8), 256, 0, stream>>>(P, P, 8, S, T4_HID);
    rope_q_from_S<<<128, 256, 0, stream>>>(S, 8, positions, c4f, s4f, qbuf);
    // 3. head-cooperative paged attention (64 splits x 32 tokens) + combine
    attn_partial_kernel<<<BATCH * NSPLIT2, 512, 0, stream>>>(
        qbuf, kv_cache, block_tables, context_lens, c4f, s4f, pm, plv, pacc);
    attn_combine_kernel<<<BATCH * HEADS, 64, 0, stream>>>(pm, plv, pacc, attn);
    // 4. ao = attn @ Wo  (Nsplit=4, SK=64)
    gemm2_kernel<32><<<dim3(4, 64), 256, 0, stream>>>(attn, Wo, P, HID, HID);
    red_stage1<<<dim3(64, 8), 256, 0, stream>>>(P, P, 8, S, T4_HID);
    red_stage2<<<64, 256, 0, stream>>>(S, 8, T4_HID, ao);
    // 5. Pprm = ao @ Wprm  ||  P = ao @ W1   (one 512-block launch)
    gemm2_dual_kernel<<<512, 256, 0, stream>>>(ao, Wprm, W1, Pprm, P);
    // 6. h1 = reduce16(P)  (SK=16, 256-block single stage)
    reduce4_kernel<<<256, 256, 0, stream>>>(P, 16, T4_FFN, h1);
    // 7. out = h1 @ W2 + prm  (Nsplit=4, SK=64, KC=128; shared 2-stage reduce)
    gemm2_kernel<128><<<dim3(4, 64), 256, 0, stream>>>(h1, W2, P, FFN, HID);
    red_stage1<<<dim3(64, 16), 256, 0, stream>>>(P, Pprm, 8, S, T4_HID);
    red_stage2<<<64, 256, 0, stream>>>(S, 16, T4_HID, out);
}